// Round 2
// baseline (988.371 us; speedup 1.0000x reference)
//
#include <hip/hip_runtime.h>
#include <hip/hip_bf16.h>
#include <hip/hip_fp16.h>

#define NN 100000
#define NE 3200000
#define IN_F 128
#define HID 32

#define NB 782          // buckets: bucket = dst >> 7, 128 nodes each
#define NBP1 (NB + 1)
#define BNODES 128
#define PBLK 782        // partition blocks
#define EPB 4096        // edges per partition block (512 thr x 8)
#define SSPAN 4608      // per-bucket record span bound (mean 4092 + 8 sigma); = 9*512

typedef __hip_bfloat16 bf16;
typedef __attribute__((ext_vector_type(8))) short s16x8;   // 8 bf16 (4 VGPRs)
typedef __attribute__((ext_vector_type(4))) float f32x4;   // MFMA C/D

// ---------------- partition: LDS counting sort, ALL global writes dense ----------------
// Also accumulates wsum[dst] (degree weight sums) via global f32 atomics; wsum is
// zeroed by hipMemsetAsync before this kernel. Self-loop (+1) folded in at k_hs.
__global__ __launch_bounds__(512) void k_part(const int* __restrict__ ei,
                                              const float* __restrict__ ew,
                                              int* __restrict__ offs,
                                              uint2* __restrict__ raw,
                                              float* __restrict__ wsum) {
    __shared__ int hist[NB];
    __shared__ int start[NB];
    __shared__ int wtot8[8];
    __shared__ uint2 sp[EPB];             // 32 KB

    int t = threadIdx.x;
    int blk = blockIdx.x;
    for (int b = t; b < NB; b += 512) hist[b] = 0;
    __syncthreads();

    unsigned pk[8]; unsigned wb[8]; int bkt[8];
    int base_e = blk * EPB;
#pragma unroll
    for (int j = 0; j < 8; j++) {
        int e = base_e + j * 512 + t;
        if (e < NE) {
            int src = __builtin_nontemporal_load(ei + e);
            int dst = __builtin_nontemporal_load(ei + NE + e);
            float w = __builtin_nontemporal_load(ew + e);
            bkt[j] = dst >> 7;
            pk[j] = (unsigned)src | ((unsigned)(dst & 127) << 20);
            wb[j] = __float_as_uint(w);
        } else bkt[j] = -1;
    }
#pragma unroll
    for (int j = 0; j < 8; j++)
        if (bkt[j] >= 0) {
            atomicAdd(&hist[bkt[j]], 1);
            int dst = (bkt[j] << 7) | (int)((pk[j] >> 20) & 127);
            atomicAdd(&wsum[dst], __uint_as_float(wb[j]));   // degree accumulation
        }
    __syncthreads();

    // exclusive scan over 782 bins (512 threads x 2, shuffle-based)
    int e0 = 2 * t, e1 = 2 * t + 1;
    int h0 = (e0 < NB) ? hist[e0] : 0;
    int h1 = (e1 < NB) ? hist[e1] : 0;
    int psum = h0 + h1;
    int lane = t & 63;
    int incl = psum;
#pragma unroll
    for (int off = 1; off < 64; off <<= 1) {
        int up = __shfl_up(incl, off, 64);
        if (lane >= off) incl += up;
    }
    int wid = t >> 6;
    if (lane == 63) wtot8[wid] = incl;
    __syncthreads();
    int woff = 0;
    for (int wj = 0; wj < wid; wj++) woff += wtot8[wj];
    int exc = woff + incl - psum;
    if (e0 < NB) start[e0] = exc;
    if (e1 < NB) start[e1] = exc + h0;
    __syncthreads();

    int total = start[NB - 1] + hist[NB - 1];
    int* orow = offs + (size_t)blk * NBP1;
    for (int b = t; b < NB; b += 512) orow[b] = start[b];
    if (t == 0) orow[NB] = total;
    __syncthreads();   // orow reads of start[] complete before cursor mutation

    // LDS counting scatter (start[] becomes cursor)
#pragma unroll
    for (int j = 0; j < 8; j++) {
        if (bkt[j] >= 0) {
            int pos = atomicAdd(&start[bkt[j]], 1);
            sp[pos] = make_uint2(pk[j], wb[j]);
        }
    }
    __syncthreads();

    // dense, coalesced copy to block-private region (written exactly once)
    uint2* r = raw + (size_t)blk * EPB;
    for (int i = t; i < total; i += 512) r[i] = sp[i];
}

// ---------------- offs transpose ([blk][bucket] -> [bucket][blk]) ----------------
__global__ __launch_bounds__(256) void k_trans(const int* __restrict__ in, int* __restrict__ out) {
    __shared__ int tile[32][33];
    int c0 = blockIdx.x * 32, r0 = blockIdx.y * 32;
    int tx = threadIdx.x & 31, ty = threadIdx.x >> 5;   // 32 x 8
    for (int i = ty; i < 32; i += 8) {
        int r = r0 + i, c = c0 + tx;
        if (r < PBLK && c < NBP1) tile[i][tx] = in[(size_t)r * NBP1 + c];
    }
    __syncthreads();
    for (int i = ty; i < 32; i += 8) {
        int c = c0 + i, r = r0 + tx;
        if (c < NBP1 && r < PBLK) out[(size_t)c * PBLK + r] = tile[tx][i];
    }
}

// ---------------- W1 -> bf16 MFMA B-fragments, lane-packed ----------------
__global__ void k_w1frag(const float* __restrict__ W1, unsigned short* __restrict__ wfrag) {
    int lane = threadIdx.x;   // 64 threads
    int q = lane >> 4;
    int n0 = lane & 15;
#pragma unroll
    for (int ks = 0; ks < 4; ks++) {
#pragma unroll
        for (int nt = 0; nt < 2; nt++) {
            int fi = ks * 2 + nt;
            int n = n0 + 16 * nt;
#pragma unroll
            for (int j = 0; j < 8; j++) {
                int k = ks * 32 + q * 8 + j;
                float v = W1[k * HID + n];
                __hip_bfloat16 bv = __float2bfloat16(v);
                wfrag[((size_t)fi * 64 + lane) * 8 + j] = *(unsigned short*)&bv;
            }
        }
    }
}

// ---------------- hs = dinv * (x @ W1) via MFMA, stored bf16; also writes dinv ----------------
__global__ __launch_bounds__(256) void k_hs(const float* __restrict__ x,
                                            const unsigned short* __restrict__ wfrag,
                                            const float* __restrict__ wsum,
                                            float* __restrict__ dinv,
                                            bf16* __restrict__ hs) {
    int t = threadIdx.x;
    int lane = t & 63;
    int wv = t >> 6;
    int base = blockIdx.x * 64 + wv * 16;
    int m = lane & 15;
    int q = lane >> 4;
    int node = base + m;

    s16x8 wf[8];
    const s16x8* wp = (const s16x8*)wfrag;
#pragma unroll
    for (int fi = 0; fi < 8; fi++) wf[fi] = wp[fi * 64 + lane];

    f32x4 acc0 = {0.f, 0.f, 0.f, 0.f};
    f32x4 acc1 = {0.f, 0.f, 0.f, 0.f};

    const float* rowp = x + (size_t)node * IN_F + q * 8;
    bool valid = (node < NN);

#pragma unroll
    for (int ks = 0; ks < 4; ks++) {
        float4 f0 = {0,0,0,0}, f1 = {0,0,0,0};
        if (valid) {
            const float4* xr = (const float4*)(rowp + ks * 32);
            f0 = xr[0]; f1 = xr[1];
        }
        union { s16x8 v; unsigned u32[4]; } af;
        __hip_bfloat162 p0 = __float22bfloat162_rn({f0.x, f0.y});
        __hip_bfloat162 p1 = __float22bfloat162_rn({f0.z, f0.w});
        __hip_bfloat162 p2 = __float22bfloat162_rn({f1.x, f1.y});
        __hip_bfloat162 p3 = __float22bfloat162_rn({f1.z, f1.w});
        af.u32[0] = *(unsigned*)&p0;
        af.u32[1] = *(unsigned*)&p1;
        af.u32[2] = *(unsigned*)&p2;
        af.u32[3] = *(unsigned*)&p3;
        acc0 = __builtin_amdgcn_mfma_f32_16x16x32_bf16(af.v, wf[ks * 2 + 0], acc0, 0, 0, 0);
        acc1 = __builtin_amdgcn_mfma_f32_16x16x32_bf16(af.v, wf[ks * 2 + 1], acc1, 0, 0, 0);
    }

    int f = lane & 15;
#pragma unroll
    for (int r = 0; r < 4; r++) {
        int n2 = base + q * 4 + r;
        if (n2 < NN) {
            float dv = rsqrtf(wsum[n2] + 1.0f);   // +1 = self-loop weight
            if (f == 0) dinv[n2] = dv;
            hs[(size_t)n2 * HID + f]      = __float2bfloat16(dv * acc0[r]);
            hs[(size_t)n2 * HID + f + 16] = __float2bfloat16(dv * acc1[r]);
        }
    }
}

// ---------------- fused per-bucket gather + LDS-atomic aggregation + epilogue ----------------
// One block per bucket (128 dst nodes). Reads this bucket's records directly from the
// partition-block-private raw regions (runid map), accumulates messages into a padded
// LDS accumulator with ds_add_f32 atomics (order-free), then applies self-loop + dinv +
// bias + relu + W2 dot per node. Eliminates the within-bucket counting sort entirely.
__global__ __launch_bounds__(512) void k_agg(const int* __restrict__ offsT,
                                             const uint2* __restrict__ raw,
                                             const bf16* __restrict__ hs,
                                             const float* __restrict__ dinv,
                                             const float* __restrict__ b1, const float* __restrict__ W2,
                                             const float* __restrict__ b2, float* __restrict__ out) {
    __shared__ unsigned short runid[SSPAN];   //  9.2 KB
    __shared__ int P[PBLK + 1];               //  3.1 KB
    __shared__ int O0[PBLK];                  //  3.1 KB
    __shared__ float acc[BNODES][33];         // 16.9 KB, padded: bank = (dl + f) & 31
    __shared__ int wt8[8];

    int t = threadIdx.x;
    int b = blockIdx.x;

    // zero accumulator
    for (int i = t; i < BNODES * 33; i += 512) ((float*)acc)[i] = 0.f;

    // run lengths for this bucket across 782 partition blocks (2 per thread)
    int e0 = 2 * t, e1 = 2 * t + 1;
    int l0 = 0, l1 = 0, o0v = 0, o1v = 0;
    if (e0 < PBLK) {
        o0v = offsT[(size_t)b * PBLK + e0];
        l0  = offsT[(size_t)(b + 1) * PBLK + e0] - o0v;
    }
    if (e1 < PBLK) {
        o1v = offsT[(size_t)b * PBLK + e1];
        l1  = offsT[(size_t)(b + 1) * PBLK + e1] - o1v;
    }
    int psum = l0 + l1;
    int lane = t & 63;
    int incl = psum;
#pragma unroll
    for (int off = 1; off < 64; off <<= 1) {
        int up = __shfl_up(incl, off, 64);
        if (lane >= off) incl += up;
    }
    int wid = t >> 6;
    if (lane == 63) wt8[wid] = incl;
    __syncthreads();          // covers wt8 + acc zeroing
    int woff = 0;
    for (int wj = 0; wj < wid; wj++) woff += wt8[wj];
    int exc = woff + incl - psum;
    if (e0 < PBLK) { P[e0] = exc;      O0[e0] = o0v; }
    if (e1 < PBLK) { P[e1] = exc + l0; O0[e1] = o1v; }
    if (t == 0) {
        int s = 0;
#pragma unroll
        for (int j = 0; j < 8; j++) s += wt8[j];
        P[PBLK] = s;
    }
    __syncthreads();

    int total = min(P[PBLK], SSPAN);

    // build d -> run map (short serial LDS fills, ~5 per run)
    for (int r = t; r < PBLK; r += 512) {
        int p0 = P[r], p1 = min(P[r + 1], SSPAN);
        for (int i = p0; i < p1; i++) runid[i] = (unsigned short)r;
    }
    __syncthreads();

    int l = t & 15;
    const __hip_bfloat162* hs2 = (const __hip_bfloat162*)hs;  // row stride 16

    // main edge loop: 16-lane groups, 16 records per round via broadcast.
    // Tail lanes hold (src=0, w=0) so the 16-wide unroll is uniform (zero-adds harmless).
    for (int k = 0; k < 9; k++) {
        int gbase = (t & ~15) + k * 512;
        if (gbase >= total) break;              // group-uniform condition
        int d = gbase + l;
        unsigned sreg = 0; float wreg = 0.f;
        if (d < total) {
            int r = runid[d];
            uint2 rec = raw[(size_t)r * EPB + O0[r] + (d - P[r])];
            sreg = rec.x; wreg = __uint_as_float(rec.y);
        }
#pragma unroll
        for (int jb = 0; jb < 16; jb += 8) {
            unsigned s0 = __shfl(sreg, jb + 0, 16), s1 = __shfl(sreg, jb + 1, 16);
            unsigned s2 = __shfl(sreg, jb + 2, 16), s3 = __shfl(sreg, jb + 3, 16);
            unsigned s4 = __shfl(sreg, jb + 4, 16), s5 = __shfl(sreg, jb + 5, 16);
            unsigned s6 = __shfl(sreg, jb + 6, 16), s7 = __shfl(sreg, jb + 7, 16);
            float w0 = __shfl(wreg, jb + 0, 16), w1 = __shfl(wreg, jb + 1, 16);
            float w2 = __shfl(wreg, jb + 2, 16), w3 = __shfl(wreg, jb + 3, 16);
            float w4 = __shfl(wreg, jb + 4, 16), w5 = __shfl(wreg, jb + 5, 16);
            float w6 = __shfl(wreg, jb + 6, 16), w7 = __shfl(wreg, jb + 7, 16);
            __hip_bfloat162 h0 = hs2[(size_t)(s0 & 0xFFFFF) * 16 + l];
            __hip_bfloat162 h1 = hs2[(size_t)(s1 & 0xFFFFF) * 16 + l];
            __hip_bfloat162 h2 = hs2[(size_t)(s2 & 0xFFFFF) * 16 + l];
            __hip_bfloat162 h3 = hs2[(size_t)(s3 & 0xFFFFF) * 16 + l];
            __hip_bfloat162 h4 = hs2[(size_t)(s4 & 0xFFFFF) * 16 + l];
            __hip_bfloat162 h5 = hs2[(size_t)(s5 & 0xFFFFF) * 16 + l];
            __hip_bfloat162 h6 = hs2[(size_t)(s6 & 0xFFFFF) * 16 + l];
            __hip_bfloat162 h7 = hs2[(size_t)(s7 & 0xFFFFF) * 16 + l];
            float2 f0 = __bfloat1622float2(h0);
            atomicAdd(&acc[(s0 >> 20) & 127][2 * l],     w0 * f0.x);
            atomicAdd(&acc[(s0 >> 20) & 127][2 * l + 1], w0 * f0.y);
            float2 f1 = __bfloat1622float2(h1);
            atomicAdd(&acc[(s1 >> 20) & 127][2 * l],     w1 * f1.x);
            atomicAdd(&acc[(s1 >> 20) & 127][2 * l + 1], w1 * f1.y);
            float2 f2 = __bfloat1622float2(h2);
            atomicAdd(&acc[(s2 >> 20) & 127][2 * l],     w2 * f2.x);
            atomicAdd(&acc[(s2 >> 20) & 127][2 * l + 1], w2 * f2.y);
            float2 f3 = __bfloat1622float2(h3);
            atomicAdd(&acc[(s3 >> 20) & 127][2 * l],     w3 * f3.x);
            atomicAdd(&acc[(s3 >> 20) & 127][2 * l + 1], w3 * f3.y);
            float2 f4 = __bfloat1622float2(h4);
            atomicAdd(&acc[(s4 >> 20) & 127][2 * l],     w4 * f4.x);
            atomicAdd(&acc[(s4 >> 20) & 127][2 * l + 1], w4 * f4.y);
            float2 f5 = __bfloat1622float2(h5);
            atomicAdd(&acc[(s5 >> 20) & 127][2 * l],     w5 * f5.x);
            atomicAdd(&acc[(s5 >> 20) & 127][2 * l + 1], w5 * f5.y);
            float2 f6 = __bfloat1622float2(h6);
            atomicAdd(&acc[(s6 >> 20) & 127][2 * l],     w6 * f6.x);
            atomicAdd(&acc[(s6 >> 20) & 127][2 * l + 1], w6 * f6.y);
            float2 f7 = __bfloat1622float2(h7);
            atomicAdd(&acc[(s7 >> 20) & 127][2 * l],     w7 * f7.x);
            atomicAdd(&acc[(s7 >> 20) & 127][2 * l + 1], w7 * f7.y);
        }
    }
    __syncthreads();

    // epilogue: 4 threads per node, 8 features each; self-loop + dinv + b1 + relu + W2
    int nl = t >> 2;            // 0..127
    int fo = (t & 3) * 8;
    int node = b * BNODES + nl;
    if (node < NN) {
        float dv = dinv[node];
        const __hip_bfloat162* selfp = hs2 + (size_t)node * 16 + (t & 3) * 4;
        float psum = 0.f;
#pragma unroll
        for (int jj = 0; jj < 4; jj++) {
            float2 fsv = __bfloat1622float2(selfp[jj]);
            int f = fo + 2 * jj;
            float v0 = dv * (acc[nl][f]     + fsv.x) + b1[f];
            float v1 = dv * (acc[nl][f + 1] + fsv.y) + b1[f + 1];
            v0 = fmaxf(v0, 0.f);
            v1 = fmaxf(v1, 0.f);
            psum += v0 * W2[f] + v1 * W2[f + 1];
        }
        psum += __shfl_xor(psum, 1, 4);
        psum += __shfl_xor(psum, 2, 4);
        if ((t & 3) == 0) out[node] = psum + b2[0];
    }
}

// ---------------- launch ----------------
extern "C" void kernel_launch(void* const* d_in, const int* in_sizes, int n_in,
                              void* d_out, int out_size, void* d_ws, size_t ws_size,
                              hipStream_t stream) {
    const float* x  = (const float*)d_in[0];
    const int*   ei = (const int*)d_in[1];
    const float* ew = (const float*)d_in[2];
    const float* W1 = (const float*)d_in[3];
    const float* b1 = (const float*)d_in[4];
    const float* W2 = (const float*)d_in[5];
    const float* b2 = (const float*)d_in[6];
    float* out = (float*)d_out;

    char* ws = (char*)d_ws;
    // ws layout (bytes), total ~37.7 MB. raw stays live through k_agg now (no overlap).
    uint2*          raw      = (uint2*)         (ws + 0);           // PBLK*EPB uint2 = 25,624,576
    int*            offs     = (int*)           (ws + 25624576);    // PBLK*NBP1 int = 2,449,224 -> pad 28,073,984
    int*            offsT    = (int*)           (ws + 28073984);    // NBP1*PBLK int -> pad 30,523,392
    bf16*           hs       = (bf16*)          (ws + 30523392);    // NN*HID bf16 = 6,400,000 -> 36,923,392
    float*          wsum     = (float*)         (ws + 36923392);    // NN floats -> 37,323,392
    float*          dinv     = (float*)         (ws + 37323392);    // NN floats -> 37,723,392
    unsigned short* wfrag    = (unsigned short*)(ws + 37723392);    // 8 KB -> 37,731,584

    (void)hipMemsetAsync(wsum, 0, NN * sizeof(float), stream);
    k_w1frag<<<1, 64, 0, stream>>>(W1, wfrag);
    k_part<<<PBLK, 512, 0, stream>>>(ei, ew, offs, raw, wsum);
    k_trans<<<dim3((NBP1 + 31) / 32, (PBLK + 31) / 32), 256, 0, stream>>>(offs, offsT);
    k_hs<<<(NN + 63) / 64, 256, 0, stream>>>(x, wfrag, wsum, dinv, hs);
    k_agg<<<NB, 512, 0, stream>>>(offsT, raw, hs, dinv, b1, W2, b2, out);
}